// Round 2
// baseline (8181.976 us; speedup 1.0000x reference)
//
#include <hip/hip_runtime.h>
#include <hip/hip_bf16.h>

typedef __attribute__((ext_vector_type(8))) short short8;
typedef __attribute__((ext_vector_type(4))) float floatx4;
typedef __attribute__((ext_vector_type(4))) unsigned int uintx4;
typedef unsigned int u32;
typedef unsigned long long u64;

#define Bb 32
#define Ss 2048
#define Ii 256
#define Hh 256

// ws layout (control+team area zeroed by hipMemsetAsync each launch):
//   u32[0]             global block ticket
//   u32[32], u32[48]   done flags per batch-half ring (mt = 0/1)
//   u32[64 + team*16]  per-team ticket counters
//   byte TEAM_OFF + team*TEAM_STRIDE : team region
//        +0     tags[4][16] u32  (line = slot*2+mt, word = wg*2+chalf)
//        +4096  data[2][32][128] u32 (packed bf16 h pairs)
//   byte gxOff (= ws_size - 128MiB, 256-aligned): gx fragments (proven layout)
#define TEAM_OFF 4096
#define TEAM_STRIDE 36864
#define MAX_TEAMS 33            // team0 (system scope) + 8 XCD x 4 SE teams
#define GXBYTES 134217728ULL    // 2048*32*64*8 u32 = 128 MiB exactly
#define CAN_TIMEOUT 16384u
#define RETRY_DEAD (1u << 20)

__device__ __forceinline__ unsigned short f2bf(float f) {
    unsigned int u = __float_as_uint(f);
    u += 0x7fffu + ((u >> 16) & 1u);   // RNE
    return (unsigned short)(u >> 16);
}
__device__ __forceinline__ float bf2f_lo(u32 w) { return __uint_as_float(w << 16); }
__device__ __forceinline__ float bf2f_hi(u32 w) { return __uint_as_float(w & 0xffff0000u); }

__device__ __forceinline__ float fast_sigmoid(float x) {
    return __builtin_amdgcn_rcpf(1.0f + __expf(-x));
}
__device__ __forceinline__ float fast_tanh(float x) {
    return 1.0f - 2.0f * __builtin_amdgcn_rcpf(__expf(2.0f * x) + 1.0f);
}

__device__ __forceinline__ void vm_drain() {
    asm volatile("s_waitcnt vmcnt(0)" ::: "memory");
}

// ---- fast path: sc0 = SE scope (coherence point: XCD L2, ~200cyc)
__device__ __forceinline__ void tag_load16_f(const u32* pt, uintx4& a, uintx4& b, uintx4& c, uintx4& d) {
    asm volatile("global_load_dwordx4 %0, %4, off sc0\n\t"
                 "global_load_dwordx4 %1, %4, off offset:16 sc0\n\t"
                 "global_load_dwordx4 %2, %4, off offset:32 sc0\n\t"
                 "global_load_dwordx4 %3, %4, off offset:48 sc0\n\t"
                 "s_waitcnt vmcnt(0)"
                 : "=v"(a), "=v"(b), "=v"(c), "=v"(d) : "v"(pt) : "memory");
}
__device__ __forceinline__ void data_load8_f(const u32* pd, uintx4 v[8]) {
    asm volatile("global_load_dwordx4 %0, %8, off sc0\n\t"
                 "global_load_dwordx4 %1, %8, off offset:64 sc0\n\t"
                 "global_load_dwordx4 %2, %8, off offset:128 sc0\n\t"
                 "global_load_dwordx4 %3, %8, off offset:192 sc0\n\t"
                 "global_load_dwordx4 %4, %8, off offset:256 sc0\n\t"
                 "global_load_dwordx4 %5, %8, off offset:320 sc0\n\t"
                 "global_load_dwordx4 %6, %8, off offset:384 sc0\n\t"
                 "global_load_dwordx4 %7, %8, off offset:448 sc0\n\t"
                 "s_waitcnt vmcnt(0)"
                 : "=v"(v[0]), "=v"(v[1]), "=v"(v[2]), "=v"(v[3]),
                   "=v"(v[4]), "=v"(v[5]), "=v"(v[6]), "=v"(v[7])
                 : "v"(pd) : "memory");
}
// ---- system path (round-0 proven: sc0 sc1 = bypass L1 + XCD L2, coherent at MALL)
// also folds the done-flag load into the same vmcnt bundle (parallel RT, ~free)
__device__ __forceinline__ void tag_load16_s_done(const u32* pt, const u32* pdone,
                                                  uintx4& a, uintx4& b, uintx4& c, uintx4& d, u32& dn) {
    asm volatile("global_load_dword %4, %6, off sc0 sc1\n\t"
                 "global_load_dwordx4 %0, %5, off sc0 sc1\n\t"
                 "global_load_dwordx4 %1, %5, off offset:16 sc0 sc1\n\t"
                 "global_load_dwordx4 %2, %5, off offset:32 sc0 sc1\n\t"
                 "global_load_dwordx4 %3, %5, off offset:48 sc0 sc1\n\t"
                 "s_waitcnt vmcnt(0)"
                 : "=v"(a), "=v"(b), "=v"(c), "=v"(d), "=v"(dn) : "v"(pt), "v"(pdone) : "memory");
}
__device__ __forceinline__ void data_load8_s(const u32* pd, uintx4 v[8]) {
    asm volatile("global_load_dwordx4 %0, %8, off sc0 sc1\n\t"
                 "global_load_dwordx4 %1, %8, off offset:64 sc0 sc1\n\t"
                 "global_load_dwordx4 %2, %8, off offset:128 sc0 sc1\n\t"
                 "global_load_dwordx4 %3, %8, off offset:192 sc0 sc1\n\t"
                 "global_load_dwordx4 %4, %8, off offset:256 sc0 sc1\n\t"
                 "global_load_dwordx4 %5, %8, off offset:320 sc0 sc1\n\t"
                 "global_load_dwordx4 %6, %8, off offset:384 sc0 sc1\n\t"
                 "global_load_dwordx4 %7, %8, off offset:448 sc0 sc1\n\t"
                 "s_waitcnt vmcnt(0)"
                 : "=v"(v[0]), "=v"(v[1]), "=v"(v[2]), "=v"(v[3]),
                   "=v"(v[4]), "=v"(v[5]), "=v"(v[6]), "=v"(v[7])
                 : "v"(pd) : "memory");
}
__device__ __forceinline__ u32 mism(const uintx4& a, const uintx4& b, const uintx4& c, const uintx4& d, u32 want) {
    return (a.x ^ want) | (a.y ^ want) | (a.z ^ want) | (a.w ^ want)
         | (b.x ^ want) | (b.y ^ want) | (b.z ^ want) | (b.w ^ want)
         | (c.x ^ want) | (c.y ^ want) | (c.z ^ want) | (c.w ^ want)
         | (d.x ^ want) | (d.y ^ want) | (d.z ^ want) | (d.w ^ want);
}

// ---------------- Phase 1: gx[t] = x_t @ Wx_all + b_all (byte-identical, proven)
__global__ __launch_bounds__(256, 2)
void lstm_gx_kernel(const float* __restrict__ x,
                    const float* __restrict__ Wf, const float* __restrict__ bfp,
                    const float* __restrict__ Wi, const float* __restrict__ bip,
                    const float* __restrict__ Wc, const float* __restrict__ bcp,
                    const float* __restrict__ Wo, const float* __restrict__ bop,
                    u32* __restrict__ gx)
{
    const int tid = threadIdx.x, wave = tid >> 6, lane = tid & 63;
    const int ln = lane & 15, lg = lane >> 4;
    const int combo = blockIdx.x & 7;
    const int tbase = (blockIdx.x >> 3) * 8;
    const int wg = ((combo & 1) << 2) + wave;
    const int chalf = (combo >> 1) & 1, mtile = combo >> 2;
    const int j0 = wg * 32 + chalf * 16, r0 = mtile * 16;
    const int wv = wg * 4 + chalf * 2 + mtile;

    const float* Wg[4] = {Wf, Wi, Wc, Wo};
    const float* bg[4] = {bfp, bip, bcp, bop};
    float bias[4];
#pragma unroll
    for (int g = 0; g < 4; ++g) bias[g] = bg[g][j0 + ln];

    short8 Bf[4][8];
#pragma unroll
    for (int g = 0; g < 4; ++g)
#pragma unroll
        for (int ks = 0; ks < 8; ++ks) {
            short8 v;
#pragma unroll
            for (int i = 0; i < 8; ++i) {
                int k = 256 + 32 * ks + 8 * lg + i;
                v[i] = (short)f2bf(Wg[g][k * Hh + (j0 + ln)]);
            }
            Bf[g][ks] = v;
        }

    for (int it = 0; it < 8; ++it) {
        int t = tbase + it;
        short8 xf[8];
#pragma unroll
        for (int ks = 0; ks < 8; ++ks) {
            const float* px = x + (r0 + ln) * (Ss * Ii) + t * Ii + 32 * ks + 8 * lg;
            floatx4 a = *(const floatx4*)px;
            floatx4 b = *(const floatx4*)(px + 4);
            short8 v;
#pragma unroll
            for (int q = 0; q < 4; ++q) { v[q] = (short)f2bf(a[q]); v[4 + q] = (short)f2bf(b[q]); }
            xf[ks] = v;
        }
        floatx4 acc[4];
#pragma unroll
        for (int g = 0; g < 4; ++g) acc[g] = (floatx4){0.f, 0.f, 0.f, 0.f};
#pragma unroll
        for (int ks = 0; ks < 8; ++ks)
#pragma unroll
            for (int g = 0; g < 4; ++g)
                acc[g] = __builtin_amdgcn_mfma_f32_16x16x32_bf16(xf[ks], Bf[g][ks], acc[g], 0, 0, 0);

        u32 o[8];
#pragma unroll
        for (int g = 0; g < 4; ++g)
#pragma unroll
            for (int rp = 0; rp < 2; ++rp) {
                float v0 = acc[g][2 * rp] + bias[g];
                float v1 = acc[g][2 * rp + 1] + bias[g];
                o[g * 2 + rp] = (u32)f2bf(v0) | ((u32)f2bf(v1) << 16);
            }
        u32* dst = gx + ((size_t)(t * 32 + wv) * 64 + lane) * 8;
        ((uintx4*)dst)[0] = (uintx4){o[0], o[1], o[2], o[3]};
        ((uintx4*)dst)[1] = (uintx4){o[4], o[5], o[6], o[7]};
    }
}

// ---------------- Phase 2: SE-local sc0 teams (canary-verified) + proven system-scope team0
__global__ __launch_bounds__(256, 1)
void lstm_rec7(const float* __restrict__ h0,
               const float* __restrict__ c0,
               const float* __restrict__ Wf,
               const float* __restrict__ Wi,
               const float* __restrict__ Wc,
               const float* __restrict__ Wo,
               float* __restrict__ out,
               u32* ws, const u32* __restrict__ gx, int maxTeams)
{
    // ---- team formation
    __shared__ u32 tinfo[2];
    if (threadIdx.x == 0) {
        u32 g = atomicAdd(ws, 1u);            // global ticket (device scope)
        u32 team, tkt;
        if (g < 8u) {                          // team0: proven system-scope backstop
            team = 0u; tkt = g;
        } else {
            u32 xcc, hwid;
            asm volatile("s_getreg_b32 %0, hwreg(HW_REG_XCC_ID)" : "=s"(xcc));
            asm volatile("s_getreg_b32 %0, hwreg(HW_REG_HW_ID)" : "=s"(hwid));
            u32 se = (hwid >> 13) & 3u;        // gfx9 HW_ID SE_ID field (4 SEs/XCD)
            team = 1u + (xcc & 7u) * 4u + se;
            tkt = (team < (u32)maxTeams) ? atomicAdd(ws + 64 + team * 16, 1u) : 0xffffu;
        }
        tinfo[0] = team; tinfo[1] = tkt;
    }
    __syncthreads();
    const u32 team = tinfo[0];
    const u32 tkt = tinfo[1];
    if (tkt >= 8u) return;                     // surplus block on this team key
    const bool fast = (team != 0u);
    const int wg = (int)tkt;
    u32* tags = (u32*)((char*)ws + TEAM_OFF + (size_t)team * TEAM_STRIDE);
    u32* data = tags + 1024;                   // +4096 bytes

    const int tid = threadIdx.x;
    const int wave = tid >> 6, lane = tid & 63;
    const int mt = wave & 1, chalf = wave >> 1;
    const int ln = lane & 15, lg = lane >> 4;
    const int j0 = wg * 32 + chalf * 16;
    const int j = j0 + ln;
    const int wv = wg * 4 + chalf * 2 + mt;
    const u32* done = ws + 32 + 16 * mt;       // per-ring done flag (system scope)

    const float* Wg[4] = {Wf, Wi, Wc, Wo};
    short8 Bfrag[4][8];
#pragma unroll
    for (int g = 0; g < 4; ++g)
#pragma unroll
        for (int ks = 0; ks < 8; ++ks) {
            short8 v;
#pragma unroll
            for (int i = 0; i < 8; ++i) {
                int k = 32 * ks + 8 * lg + i;
                v[i] = (short)f2bf(Wg[g][k * Hh + j]);
            }
            Bfrag[g][ks] = v;
        }

    // publish h[4] into `slot` with sentinel `tag` using this team's scope
    auto publish = [&](int slot, u32 tag, const float h[4]) {
        u32 wrd[4];
#pragma unroll
        for (int r = 0; r < 4; ++r) {
            float partner = __shfl_xor(h[r], 1);
            wrd[r] = (u32)f2bf(h[r]) | ((u32)f2bf(partner) << 16);  // valid on even lanes
        }
        u32* pd = data + slot * 4096 + (16 * mt + 4 * lg) * 128 + (j >> 1);
        if ((ln & 1) == 0) {
            if (fast) {
                asm volatile("global_store_dword %4, %0, off sc0\n\t"
                             "global_store_dword %4, %1, off offset:512 sc0\n\t"
                             "global_store_dword %4, %2, off offset:1024 sc0\n\t"
                             "global_store_dword %4, %3, off offset:1536 sc0"
                             :: "v"(wrd[0]), "v"(wrd[1]), "v"(wrd[2]), "v"(wrd[3]), "v"(pd) : "memory");
            } else {
                asm volatile("global_store_dword %4, %0, off sc0 sc1\n\t"
                             "global_store_dword %4, %1, off offset:512 sc0 sc1\n\t"
                             "global_store_dword %4, %2, off offset:1024 sc0 sc1\n\t"
                             "global_store_dword %4, %3, off offset:1536 sc0 sc1"
                             :: "v"(wrd[0]), "v"(wrd[1]), "v"(wrd[2]), "v"(wrd[3]), "v"(pd) : "memory");
            }
        }
        vm_drain();   // release: data stores acked before sentinel
        if (lane == 0) {
            u32* ptg = tags + (slot * 2 + mt) * 16 + (wg * 2 + chalf);
            if (fast)
                asm volatile("global_store_dword %0, %1, off sc0" :: "v"(ptg), "v"(tag) : "memory");
            else
                asm volatile("global_store_dword %0, %1, off sc0 sc1" :: "v"(ptg), "v"(tag) : "memory");
        }
    };

    float hv0[4];
#pragma unroll
    for (int r = 0; r < 4; ++r) hv0[r] = h0[(16 * mt + 4 * lg + r) * Hh + j];

    // ---- canary (fast teams only): exchange f2bf(h0) via slot1/tag1 through the sc0
    // path and bit-verify against locally recomputed values. Failure => exit silently
    // (team0 and/or other teams cover the output). Slot1 is overwritten at end of t=0.
    if (fast) {
        publish(1, 1u, hv0);
        const u32* ptc = tags + (1 * 2 + mt) * 16;
        u32 it = 0;
        bool ok = true;
        for (;;) {
            uintx4 a, b, c, d;
            tag_load16_f(ptc, a, b, c, d);
            if (!__any((int)(mism(a, b, c, d, 1u) != 0))) break;
            if (++it >= CAN_TIMEOUT) { ok = false; break; }
        }
        if (ok) {
            uintx4 dv[8];
            data_load8_f(data + 1 * 4096 + (16 * mt + ln) * 128 + 4 * lg, dv);
            const float* hr = h0 + (16 * mt + ln) * Hh;
#pragma unroll
            for (int ks = 0; ks < 8; ++ks)
#pragma unroll
                for (int q = 0; q < 4; ++q) {
                    int ci = 4 * lg + 16 * ks + q;
                    u32 w = (u32)f2bf(hr[2 * ci]) | ((u32)f2bf(hr[2 * ci + 1]) << 16);
                    ok &= (dv[ks][q] == w);
                }
        }
        if (__any((int)(!ok))) return;   // sc0 path not trustworthy here: bail out, write nothing
    }

    float cst[4], hl[4];
#pragma unroll
    for (int r = 0; r < 4; ++r) {
        cst[r] = c0[(16 * mt + 4 * lg + r) * Hh + j];
        hl[r] = 0.0f;
    }

    // ---- publish h0 (tag 1) into slot 0, then run the recurrence
    publish(0, 1u, hv0);

    uintx4 g0, g1;
    {
        const uintx4* p = (const uintx4*)(gx + ((size_t)wv * 64 + lane) * 8);
        g0 = p[0]; g1 = p[1];
    }

    bool aborted = false;
    for (int t = 0; t < Ss; ++t) {
        const int slot = t & 1;
        const u32 want = (u32)(t + 1);
        const u32* pt = tags + (slot * 2 + mt) * 16;

        // ---- sentinel poll
        {
            u32 it = 0;
            for (;;) {
                uintx4 a, b, c, d;
                u32 bad;
                if (fast) {
                    tag_load16_f(pt, a, b, c, d);
                    bad = mism(a, b, c, d, want);
                } else {
                    u32 dn;
                    tag_load16_s_done(pt, done, a, b, c, d, dn);
                    if (dn) { aborted = true; break; }   // a complete ring finished: stop writing
                    bad = mism(a, b, c, d, want);
                }
                if (!__any((int)(bad != 0))) break;
                ++it;
                if (fast && (it & 1023u) == 0u) {        // stuck? check done at system scope
                    u32 dn;
                    asm volatile("global_load_dword %0, %1, off sc0 sc1\n\ts_waitcnt vmcnt(0)"
                                 : "=v"(dn) : "v"(done) : "memory");
                    if (dn) { aborted = true; break; }
                }
                if (it >= RETRY_DEAD) { aborted = true; break; }
            }
            if (aborted) break;
        }

        // ---- one-shot data read: rows 16mt+ln, packed pairs == A-fragments
        uintx4 dv[8];
        const u32* pd = data + slot * 4096 + (16 * mt + ln) * 128 + 4 * lg;
        if (fast) data_load8_f(pd, dv); else data_load8_s(pd, dv);

        // ---- acc init from gx (prefetched last iteration, off critical path)
        floatx4 acc[4];
        acc[0] = (floatx4){bf2f_lo(g0.x), bf2f_hi(g0.x), bf2f_lo(g0.y), bf2f_hi(g0.y)};
        acc[1] = (floatx4){bf2f_lo(g0.z), bf2f_hi(g0.z), bf2f_lo(g0.w), bf2f_hi(g0.w)};
        acc[2] = (floatx4){bf2f_lo(g1.x), bf2f_hi(g1.x), bf2f_lo(g1.y), bf2f_hi(g1.y)};
        acc[3] = (floatx4){bf2f_lo(g1.z), bf2f_hi(g1.z), bf2f_lo(g1.w), bf2f_hi(g1.w)};

        // ---- h-GEMM: 32 MFMAs
#pragma unroll
        for (int ks = 0; ks < 8; ++ks) {
            union { uintx4 u; short8 s; } cv;
            cv.u = dv[ks];
#pragma unroll
            for (int g = 0; g < 4; ++g)
                acc[g] = __builtin_amdgcn_mfma_f32_16x16x32_bf16(cv.s, Bfrag[g][ks], acc[g], 0, 0, 0);
        }

        // ---- gates + state update
        float hnew[4];
#pragma unroll
        for (int r = 0; r < 4; ++r) {
            float fg = fast_sigmoid(acc[0][r]);
            float ig = fast_sigmoid(acc[1][r]);
            float cd = fast_tanh(acc[2][r]);
            float og = fast_sigmoid(acc[3][r]);
            float c  = cst[r] * fg + ig * cd;
            cst[r] = c;
            hnew[r] = og * fast_tanh(c);
            hl[r] = hnew[r];
        }

        // ---- publish first (unblock peers); THEN out stores and gx prefetch, so the
        // release drain never waits on HBM-latency loads (they drain inside next poll)
        publish((t + 1) & 1, (u32)(t + 2), hnew);
#pragma unroll
        for (int r = 0; r < 4; ++r)
            out[(16 * mt + 4 * lg + r) * (Ss * Hh) + t * Hh + j] = hnew[r];
        if (t + 1 < Ss) {
            const uintx4* pn = (const uintx4*)(gx + ((size_t)((t + 1) * 32 + wv) * 64 + lane) * 8);
            g0 = pn[0]; g1 = pn[1];
        }
    }

    if (!aborted) {
        float* hfo = out + Bb * Ss * Hh;
        float* cfo = hfo + Bb * Hh;
#pragma unroll
        for (int r = 0; r < 4; ++r) {
            int b = 16 * mt + 4 * lg + r;
            hfo[b * Hh + j] = hl[r];
            cfo[b * Hh + j] = cst[r];
        }
        vm_drain();
        __hip_atomic_store((u32*)done, 1u, __ATOMIC_RELAXED, __HIP_MEMORY_SCOPE_AGENT);
    }
}

extern "C" void kernel_launch(void* const* d_in, const int* in_sizes, int n_in,
                              void* d_out, int out_size, void* d_ws, size_t ws_size,
                              hipStream_t stream) {
    (void)in_sizes; (void)n_in; (void)out_size;
    const float* x  = (const float*)d_in[0];
    const float* h0 = (const float*)d_in[1];
    const float* c0 = (const float*)d_in[2];
    const float* Wf = (const float*)d_in[3]; const float* bf = (const float*)d_in[4];
    const float* Wi = (const float*)d_in[5]; const float* bi = (const float*)d_in[6];
    const float* Wc = (const float*)d_in[7]; const float* bc = (const float*)d_in[8];
    const float* Wo = (const float*)d_in[9]; const float* bo = (const float*)d_in[10];

    // gx sits at the top of the workspace; teams use whatever is below it.
    size_t gxOff = (ws_size - (size_t)GXBYTES) & ~(size_t)255;
    int maxTeams = (int)((gxOff - TEAM_OFF) / TEAM_STRIDE);
    if (maxTeams > MAX_TEAMS) maxTeams = MAX_TEAMS;
    if (maxTeams < 1) maxTeams = 1;
    u32* gx = (u32*)((char*)d_ws + gxOff);

    // zero control words + all team tags (tickets, done flags, sentinels)
    hipMemsetAsync(d_ws, 0, (size_t)TEAM_OFF + (size_t)maxTeams * TEAM_STRIDE, stream);

    hipLaunchKernelGGL(lstm_gx_kernel, dim3(2048), dim3(256), 0, stream,
                       x, Wf, bf, Wi, bi, Wc, bc, Wo, bo, gx);
    hipLaunchKernelGGL(lstm_rec7, dim3(264), dim3(256), 0, stream,
                       h0, c0, Wf, Wi, Wc, Wo, (float*)d_out, (u32*)d_ws, gx, maxTeams);
}

// Round 3
// 6215.767 us; speedup vs baseline: 1.3163x; 1.3163x over previous
//
#include <hip/hip_runtime.h>
#include <hip/hip_bf16.h>

typedef __attribute__((ext_vector_type(8))) short short8;
typedef __attribute__((ext_vector_type(4))) float floatx4;
typedef __attribute__((ext_vector_type(4))) unsigned int uintx4;
typedef unsigned int u32;

#define Bb 32
#define Ss 2048
#define Ii 256
#define Hh 256

// ws layout:
//   [4096, 53248)   data: u32 data[3][32][128] — value-validated h exchange, slot = t%3
//                   word = packed bf16 pair | 0x4000 (written, lo bit14) | parity<<30 (hi bit14)
//                   (|h|<=1.0 => bf16 bit14 always 0 => both bits are free; 0xAAAAAAAA and
//                    0x00000000 poison both fail the check)
//   [65536, ...)    gx: bf16 pre-activation fragments (round-0 layout, proven)
#define DATA_OFF 4096
#define GX_OFF   65536
#define RETRY_DEAD (1u << 22)

__device__ __forceinline__ unsigned short f2bf(float f) {
    unsigned int u = __float_as_uint(f);
    u += 0x7fffu + ((u >> 16) & 1u);   // RNE
    return (unsigned short)(u >> 16);
}
__device__ __forceinline__ float bf2f_lo(u32 w) { return __uint_as_float(w << 16); }
__device__ __forceinline__ float bf2f_hi(u32 w) { return __uint_as_float(w & 0xffff0000u); }

__device__ __forceinline__ float fast_sigmoid(float x) {
    return __builtin_amdgcn_rcpf(1.0f + __expf(-x));
}
__device__ __forceinline__ float fast_tanh(float x) {
    return 1.0f - 2.0f * __builtin_amdgcn_rcpf(__expf(2.0f * x) + 1.0f);
}

// device-coherent batched poll load (sc0 sc1 = system scope, served at MALL — proven path)
__device__ __forceinline__ void data_load8_s(const u32* pd, uintx4 v[8]) {
    asm volatile("global_load_dwordx4 %0, %8, off sc0 sc1\n\t"
                 "global_load_dwordx4 %1, %8, off offset:64 sc0 sc1\n\t"
                 "global_load_dwordx4 %2, %8, off offset:128 sc0 sc1\n\t"
                 "global_load_dwordx4 %3, %8, off offset:192 sc0 sc1\n\t"
                 "global_load_dwordx4 %4, %8, off offset:256 sc0 sc1\n\t"
                 "global_load_dwordx4 %5, %8, off offset:320 sc0 sc1\n\t"
                 "global_load_dwordx4 %6, %8, off offset:384 sc0 sc1\n\t"
                 "global_load_dwordx4 %7, %8, off offset:448 sc0 sc1\n\t"
                 "s_waitcnt vmcnt(0)"
                 : "=v"(v[0]), "=v"(v[1]), "=v"(v[2]), "=v"(v[3]),
                   "=v"(v[4]), "=v"(v[5]), "=v"(v[6]), "=v"(v[7])
                 : "v"(pd) : "memory");
}

// ---------------- Phase 1: gx[t] = x_t @ Wx_all + b_all (byte-identical, proven)
__global__ __launch_bounds__(256, 2)
void lstm_gx_kernel(const float* __restrict__ x,
                    const float* __restrict__ Wf, const float* __restrict__ bfp,
                    const float* __restrict__ Wi, const float* __restrict__ bip,
                    const float* __restrict__ Wc, const float* __restrict__ bcp,
                    const float* __restrict__ Wo, const float* __restrict__ bop,
                    u32* __restrict__ gx)
{
    const int tid = threadIdx.x, wave = tid >> 6, lane = tid & 63;
    const int ln = lane & 15, lg = lane >> 4;
    const int combo = blockIdx.x & 7;
    const int tbase = (blockIdx.x >> 3) * 8;
    const int wg = ((combo & 1) << 2) + wave;
    const int chalf = (combo >> 1) & 1, mtile = combo >> 2;
    const int j0 = wg * 32 + chalf * 16, r0 = mtile * 16;
    const int wv = wg * 4 + chalf * 2 + mtile;

    const float* Wg[4] = {Wf, Wi, Wc, Wo};
    const float* bg[4] = {bfp, bip, bcp, bop};
    float bias[4];
#pragma unroll
    for (int g = 0; g < 4; ++g) bias[g] = bg[g][j0 + ln];

    short8 Bf[4][8];
#pragma unroll
    for (int g = 0; g < 4; ++g)
#pragma unroll
        for (int ks = 0; ks < 8; ++ks) {
            short8 v;
#pragma unroll
            for (int i = 0; i < 8; ++i) {
                int k = 256 + 32 * ks + 8 * lg + i;
                v[i] = (short)f2bf(Wg[g][k * Hh + (j0 + ln)]);
            }
            Bf[g][ks] = v;
        }

    for (int it = 0; it < 8; ++it) {
        int t = tbase + it;
        short8 xf[8];
#pragma unroll
        for (int ks = 0; ks < 8; ++ks) {
            const float* px = x + (r0 + ln) * (Ss * Ii) + t * Ii + 32 * ks + 8 * lg;
            floatx4 a = *(const floatx4*)px;
            floatx4 b = *(const floatx4*)(px + 4);
            short8 v;
#pragma unroll
            for (int q = 0; q < 4; ++q) { v[q] = (short)f2bf(a[q]); v[4 + q] = (short)f2bf(b[q]); }
            xf[ks] = v;
        }
        floatx4 acc[4];
#pragma unroll
        for (int g = 0; g < 4; ++g) acc[g] = (floatx4){0.f, 0.f, 0.f, 0.f};
#pragma unroll
        for (int ks = 0; ks < 8; ++ks)
#pragma unroll
            for (int g = 0; g < 4; ++g)
                acc[g] = __builtin_amdgcn_mfma_f32_16x16x32_bf16(xf[ks], Bf[g][ks], acc[g], 0, 0, 0);

        u32 o[8];
#pragma unroll
        for (int g = 0; g < 4; ++g)
#pragma unroll
            for (int rp = 0; rp < 2; ++rp) {
                float v0 = acc[g][2 * rp] + bias[g];
                float v1 = acc[g][2 * rp + 1] + bias[g];
                o[g * 2 + rp] = (u32)f2bf(v0) | ((u32)f2bf(v1) << 16);
            }
        u32* dst = gx + ((size_t)(t * 32 + wv) * 64 + lane) * 8;
        ((uintx4*)dst)[0] = (uintx4){o[0], o[1], o[2], o[3]};
        ((uintx4*)dst)[1] = (uintx4){o[4], o[5], o[6], o[7]};
    }
}

// ---------------- Phase 2: 8 blocks, tag-free value-validated exchange, fire-and-forget publish
__global__ __launch_bounds__(256, 1)
void lstm_rec8(const float* __restrict__ h0,
               const float* __restrict__ c0,
               const float* __restrict__ Wf,
               const float* __restrict__ Wi,
               const float* __restrict__ Wc,
               const float* __restrict__ Wo,
               float* __restrict__ out,
               u32* data, const u32* __restrict__ gx)
{
    const int wg = blockIdx.x;
    const int tid = threadIdx.x;
    const int wave = tid >> 6, lane = tid & 63;
    const int mt = wave & 1, chalf = wave >> 1;   // batch-half, col-block
    const int ln = lane & 15, lg = lane >> 4;
    const int j0 = wg * 32 + chalf * 16;
    const int j = j0 + ln;
    const int wv = wg * 4 + chalf * 2 + mt;       // gx fragment slot (matches writer)

    const float* Wg[4] = {Wf, Wi, Wc, Wo};
    short8 Bfrag[4][8];                            // h-part weights, full K=256
#pragma unroll
    for (int g = 0; g < 4; ++g)
#pragma unroll
        for (int ks = 0; ks < 8; ++ks) {
            short8 v;
#pragma unroll
            for (int i = 0; i < 8; ++i) {
                int k = 32 * ks + 8 * lg + i;
                v[i] = (short)f2bf(Wg[g][k * Hh + j]);
            }
            Bfrag[g][ks] = v;
        }

    float cst[4], hl[4];
#pragma unroll
    for (int r = 0; r < 4; ++r) {
        cst[r] = c0[(16 * mt + 4 * lg + r) * Hh + j];
        hl[r] = 0.0f;
    }

    // gates + state update + encoded fire-and-forget publish + out stores
    auto step_tail = [&](floatx4 (&acc)[4], int t, int sw_) {
        float hnew[4];
#pragma unroll
        for (int r = 0; r < 4; ++r) {
            float fg = fast_sigmoid(acc[0][r]);
            float ig = fast_sigmoid(acc[1][r]);
            float cd = fast_tanh(acc[2][r]);
            float og = fast_sigmoid(acc[3][r]);
            float c  = cst[r] * fg + ig * cd;
            cst[r] = c;
            hnew[r] = og * fast_tanh(c);
            hl[r] = hnew[r];
        }
        const u32 tb = 0x4000u | ((u32)(t & 1) << 30);   // written-bit + parity
        u32 wrd[4];
#pragma unroll
        for (int r = 0; r < 4; ++r) {
            float partner = __shfl_xor(hnew[r], 1);
            wrd[r] = ((u32)f2bf(hnew[r]) | ((u32)f2bf(partner) << 16)) | tb;  // valid on even lanes
        }
        u32* pw = data + sw_ * 4096 + (16 * mt + 4 * lg) * 128 + (j >> 1);
        if ((ln & 1) == 0) {
            asm volatile("global_store_dword %4, %0, off sc0 sc1\n\t"
                         "global_store_dword %4, %1, off offset:512 sc0 sc1\n\t"
                         "global_store_dword %4, %2, off offset:1024 sc0 sc1\n\t"
                         "global_store_dword %4, %3, off offset:1536 sc0 sc1"
                         :: "v"(wrd[0]), "v"(wrd[1]), "v"(wrd[2]), "v"(wrd[3]), "v"(pw)
                         : "memory");
        }
        // NO drain: consumers validate by value; next poll's vmcnt(0) drains for slot-reuse order
#pragma unroll
        for (int r = 0; r < 4; ++r)
            out[(16 * mt + 4 * lg + r) * (Ss * Hh) + t * Hh + j] = hnew[r];
    };

    auto run_mfma = [&](short8 (&afr)[8], floatx4 (&acc)[4]) {
#pragma unroll
        for (int ks = 0; ks < 8; ++ks)
#pragma unroll
            for (int g = 0; g < 4; ++g)
                acc[g] = __builtin_amdgcn_mfma_f32_16x16x32_bf16(afr[ks], Bfrag[g][ks], acc[g], 0, 0, 0);
    };

    uintx4 g0, g1;
    {
        const uintx4* p = (const uintx4*)(gx + ((size_t)wv * 64 + lane) * 8);
        g0 = p[0]; g1 = p[1];
    }

    // ---- step 0: A-fragments straight from h0 (global, fully available — no exchange)
    {
        short8 a0[8];
        const float* hr = h0 + (16 * mt + ln) * Hh;
#pragma unroll
        for (int ks = 0; ks < 8; ++ks) {
            floatx4 a = *(const floatx4*)(hr + 32 * ks + 8 * lg);
            floatx4 b = *(const floatx4*)(hr + 32 * ks + 8 * lg + 4);
            short8 v;
#pragma unroll
            for (int q = 0; q < 4; ++q) { v[q] = (short)f2bf(a[q]); v[4 + q] = (short)f2bf(b[q]); }
            a0[ks] = v;
        }
        floatx4 acc[4];
        acc[0] = (floatx4){bf2f_lo(g0.x), bf2f_hi(g0.x), bf2f_lo(g0.y), bf2f_hi(g0.y)};
        acc[1] = (floatx4){bf2f_lo(g0.z), bf2f_hi(g0.z), bf2f_lo(g0.w), bf2f_hi(g0.w)};
        acc[2] = (floatx4){bf2f_lo(g1.x), bf2f_hi(g1.x), bf2f_lo(g1.y), bf2f_hi(g1.y)};
        acc[3] = (floatx4){bf2f_lo(g1.z), bf2f_hi(g1.z), bf2f_lo(g1.w), bf2f_hi(g1.w)};
        {   // prefetch gx[1]
            const uintx4* pn = (const uintx4*)(gx + ((size_t)(1 * 32 + wv) * 64 + lane) * 8);
            g0 = pn[0]; g1 = pn[1];
        }
        run_mfma(a0, acc);
        step_tail(acc, 0, 0);
    }

    // ---- steps 1..Ss-1: poll slot (t-1)%3 for parity-validated h_{t-1}
    int sr = 0, sw = 1;
    for (int t = 1; t < Ss; ++t) {
        const u32 want = 0x4000u | ((u32)((t - 1) & 1) << 30);
        const u32* pd = data + sr * 4096 + (16 * mt + ln) * 128 + 4 * lg;
        uintx4 dv[8];
        {
            u32 it = 0;
            for (;;) {
                data_load8_s(pd, dv);   // vmcnt(0) also drains our prior stores (slot-reuse order)
                u32 bad = 0;
#pragma unroll
                for (int ks = 0; ks < 8; ++ks) {
                    bad |= (dv[ks].x & 0x40004000u) ^ want;
                    bad |= (dv[ks].y & 0x40004000u) ^ want;
                    bad |= (dv[ks].z & 0x40004000u) ^ want;
                    bad |= (dv[ks].w & 0x40004000u) ^ want;
                }
                if (!__any((int)(bad != 0))) break;
                if (++it >= RETRY_DEAD) break;   // terminate, never hang
            }
        }
        short8 afr[8];
#pragma unroll
        for (int ks = 0; ks < 8; ++ks) {
            union { uintx4 u; short8 s; } cv;
            cv.u = (uintx4){dv[ks].x & 0xBFFFBFFFu, dv[ks].y & 0xBFFFBFFFu,
                            dv[ks].z & 0xBFFFBFFFu, dv[ks].w & 0xBFFFBFFFu};
            afr[ks] = cv.s;
        }

        floatx4 acc[4];
        acc[0] = (floatx4){bf2f_lo(g0.x), bf2f_hi(g0.x), bf2f_lo(g0.y), bf2f_hi(g0.y)};
        acc[1] = (floatx4){bf2f_lo(g0.z), bf2f_hi(g0.z), bf2f_lo(g0.w), bf2f_hi(g0.w)};
        acc[2] = (floatx4){bf2f_lo(g1.x), bf2f_hi(g1.x), bf2f_lo(g1.y), bf2f_hi(g1.y)};
        acc[3] = (floatx4){bf2f_lo(g1.z), bf2f_hi(g1.z), bf2f_lo(g1.w), bf2f_hi(g1.w)};
        if (t + 1 < Ss) {   // prefetch gx[t+1], overlaps MFMA + gates + next poll
            const uintx4* pn = (const uintx4*)(gx + ((size_t)((t + 1) * 32 + wv) * 64 + lane) * 8);
            g0 = pn[0]; g1 = pn[1];
        }

        run_mfma(afr, acc);
        step_tail(acc, t, sw);

        sr = sw; sw = (sw == 2) ? 0 : sw + 1;
    }

    float* hfo = out + Bb * Ss * Hh;
    float* cfo = hfo + Bb * Hh;
#pragma unroll
    for (int r = 0; r < 4; ++r) {
        int b = 16 * mt + 4 * lg + r;
        hfo[b * Hh + j] = hl[r];
        cfo[b * Hh + j] = cst[r];
    }
}

extern "C" void kernel_launch(void* const* d_in, const int* in_sizes, int n_in,
                              void* d_out, int out_size, void* d_ws, size_t ws_size,
                              hipStream_t stream) {
    (void)in_sizes; (void)n_in; (void)out_size; (void)ws_size;
    const float* x  = (const float*)d_in[0];
    const float* h0 = (const float*)d_in[1];
    const float* c0 = (const float*)d_in[2];
    const float* Wf = (const float*)d_in[3]; const float* bf = (const float*)d_in[4];
    const float* Wi = (const float*)d_in[5]; const float* bi = (const float*)d_in[6];
    const float* Wc = (const float*)d_in[7]; const float* bc = (const float*)d_in[8];
    const float* Wo = (const float*)d_in[9]; const float* bo = (const float*)d_in[10];

    u32* data = (u32*)((char*)d_ws + DATA_OFF);
    u32* gx   = (u32*)((char*)d_ws + GX_OFF);

    // zero the 48 KB exchange region: all-zero = "unwritten" under the bit14 validity code
    hipMemsetAsync(d_ws, 0, 65536, stream);

    hipLaunchKernelGGL(lstm_gx_kernel, dim3(2048), dim3(256), 0, stream,
                       x, Wf, bf, Wi, bi, Wc, bc, Wo, bo, gx);
    hipLaunchKernelGGL(lstm_rec8, dim3(8), dim3(256), 0, stream,
                       h0, c0, Wf, Wi, Wc, Wo, (float*)d_out, data, gx);
}